// Round 1
// 494.503 us; speedup vs baseline: 1.0076x; 1.0076x over previous
//
#include <hip/hip_runtime.h>
#include <stdint.h>
#include <stddef.h>

#define D_MODEL 1024
#define SEQ     4096
#define BATCH   4
#define MTOT    (BATCH*SEQ)     // 16384
#define NWIN    63

typedef __bf16 bf16;
typedef __bf16 bf16x8 __attribute__((ext_vector_type(8)));
typedef __bf16 bf16x4 __attribute__((ext_vector_type(4)));
typedef float  floatx4 __attribute__((ext_vector_type(4)));

// async global->LDS, 16B per lane. LDS dest must be wave-uniform base + lane*16.
__device__ __forceinline__ void async_ld16(const void* g, void* l) {
  __builtin_amdgcn_global_load_lds(
      (const __attribute__((address_space(1))) unsigned int*)g,
      (__attribute__((address_space(3))) unsigned int*)l,
      16, 0, 0);
}

// ---------------- elementwise converts ----------------

__global__ __launch_bounds__(256)
void cvt_x_kernel(const float* __restrict__ x, bf16* __restrict__ xb)
{
  const int i = blockIdx.x * 256 + threadIdx.x;   // exactly 4M threads (16M elems /4)
  const float4 v = ((const float4*)x)[i];
  bf16x4 o = { (bf16)v.x, (bf16)v.y, (bf16)v.z, (bf16)v.w };
  ((bf16x4*)xb)[i] = o;
}

// W (fp32, [K][N]) -> Wt (bf16, [N][K]), packed: rows 0..1023=Wq^T, ..., 3072..4095=Wo^T
__global__ __launch_bounds__(256)
void cvt_wt_kernel(const float* __restrict__ W0, const float* __restrict__ W1,
                   const float* __restrict__ W2, const float* __restrict__ W3,
                   bf16* __restrict__ wt)
{
  __shared__ float tile[32][33];
  const float* Wsel = (blockIdx.z == 0) ? W0 : (blockIdx.z == 1) ? W1
                    : (blockIdx.z == 2) ? W2 : W3;
  bf16* Wt = wt + (size_t)blockIdx.z * D_MODEL * D_MODEL;
  const int tx = threadIdx.x & 31, ty = threadIdx.x >> 5;  // 32 x 8
  const int tn = blockIdx.x * 32, tk = blockIdx.y * 32;
#pragma unroll
  for (int j = 0; j < 32; j += 8)
    tile[ty + j][tx] = Wsel[(size_t)(tk + ty + j) * D_MODEL + (tn + tx)];
  __syncthreads();
#pragma unroll
  for (int j = 0; j < 32; j += 8)
    Wt[(size_t)(tn + ty + j) * D_MODEL + (tk + tx)] = (bf16)tile[tx][ty + j];
}

// ---------------- GEMM core: m97 structure ----------------
// 128x128 tile, BK=64, 4 waves (2x2 of 64x64), mfma_f32_16x16x32_bf16, BT form.
// global_load_lds width-16 staging into a SINGLE 32KB LDS buffer (As+Bs 16KB each),
// two barriers per K-step. The __syncthreads() after staging drains vmcnt(0),
// making the async loads visible; occupancy ~5 blocks/CU at 32KB LDS.
// LDS fragment layout: frag f (0..15) at bytes [f*1024 + lane*16], i.e. wave-uniform
// base + lane*16 — exactly what global_load_lds requires.
__device__ __forceinline__ void gemm_core_lds(const bf16* __restrict__ A,
                                              const bf16* __restrict__ Bt,
                                              int m0, int n0,
                                              bf16* As, bf16* Bs,
                                              floatx4 (&acc)[4][4],
                                              int w, int l)
{
  const int ll = l & 15, lh = l >> 4;
  const int wm = w >> 1, wn = w & 1;

  // per-lane global bases, hoisted out of the K-loop
  const bf16* Abase = A  + (size_t)(m0 + ll) * D_MODEL + lh * 8;
  const bf16* Bbase = Bt + (size_t)(n0 + ll) * D_MODEL + lh * 8;

  for (int t = 0; t < 16; ++t) {         // K = 1024 = 16 * 64
    const int k0 = t << 6;
#pragma unroll
    for (int i = 0; i < 4; ++i) {
      const int f = w * 4 + i;           // frag id 0..15
      const int mt = f & 7, kk = f >> 3; // row-block of 16, k-half of 32
      async_ld16(Abase + (size_t)(mt * 16) * D_MODEL + (k0 + kk * 32),
                 &As[f * 512 + l * 8]);
      async_ld16(Bbase + (size_t)(mt * 16) * D_MODEL + (k0 + kk * 32),
                 &Bs[f * 512 + l * 8]);
    }
    __syncthreads();                     // vmcnt(0) drain + barrier: tile ready
#pragma unroll
    for (int kk = 0; kk < 2; ++kk) {
      bf16x8 af[4], bfr[4];
#pragma unroll
      for (int tt = 0; tt < 4; ++tt) {
        af[tt]  = *(const bf16x8*)&As[(kk * 8 + wm * 4 + tt) * 512 + l * 8];
        bfr[tt] = *(const bf16x8*)&Bs[(kk * 8 + wn * 4 + tt) * 512 + l * 8];
      }
#pragma unroll
      for (int mt = 0; mt < 4; ++mt)
#pragma unroll
        for (int nt = 0; nt < 4; ++nt)
          acc[mt][nt] = __builtin_amdgcn_mfma_f32_16x16x32_bf16(af[mt], bfr[nt], acc[mt][nt], 0, 0, 0);
    }
    __syncthreads();                     // all reads done before next stage overwrites
  }
}

// ---------------- fused QKV projection GEMM ----------------
__global__ __launch_bounds__(256)
void gemm_qkv(const bf16* __restrict__ A, const bf16* __restrict__ Bt,
              const float* __restrict__ bq, const float* __restrict__ bk,
              const float* __restrict__ bv,
              bf16* __restrict__ qo, bf16* __restrict__ ko, bf16* __restrict__ vto)
{
  __shared__ __attribute__((aligned(16))) bf16 As[8192];   // 16KB, single buffer
  __shared__ __attribute__((aligned(16))) bf16 Bs[8192];   // 16KB
  const int tid = threadIdx.x;
  const int w = tid >> 6, l = tid & 63;
  const int ll = l & 15, lh = l >> 4;
  const int wm = w >> 1, wn = w & 1;

  const int idx = blockIdx.x;            // 0..3071
  const int xcd = idx & 7;
  const int local = idx >> 3;            // 0..383 = sub*96 + n*4 + msub
  const int msub = local & 3;
  const int nblk = (local >> 2) % 24;
  const int sub  = local / 96;           // 0..3
  const int mblk = xcd * 16 + sub * 4 + msub;
  const int m0 = mblk * 128, n0 = nblk * 128;

  floatx4 acc[4][4];
#pragma unroll
  for (int i = 0; i < 4; ++i)
#pragma unroll
    for (int j = 0; j < 4; ++j) acc[i][j] = (floatx4)0.f;

  gemm_core_lds(A, Bt, m0, n0, As, Bs, acc, w, l);

  const int sel = n0 >> 10;              // 0=q 1=k 2=v (block-uniform)
  const int ncl = n0 & 1023;
  const float* bias = (sel == 0) ? bq : (sel == 1) ? bk : bv;

#pragma unroll
  for (int mt = 0; mt < 4; ++mt) {
#pragma unroll
    for (int nt = 0; nt < 4; ++nt) {
      const int colL = ncl + wn * 64 + nt * 16 + ll;
      const float bvv = bias[colL];
#pragma unroll
      for (int r = 0; r < 4; ++r) {
        const int row = m0 + wm * 64 + mt * 16 + lh * 4 + r;
        const float v = acc[mt][nt][r] + bvv;
        if (sel == 0) {
          qo[(size_t)row * D_MODEL + colL] = (bf16)v;
        } else if (sel == 1) {
          ko[(size_t)row * D_MODEL + colL] = (bf16)v;
        } else {
          const int bb = row >> 12, s = row & 4095;
          vto[((size_t)bb * D_MODEL + colL) * SEQ + s] = (bf16)v;
        }
      }
    }
  }
}

// ---------------- output projection GEMM (fp32 out) ----------------
__global__ __launch_bounds__(256)
void gemm_out(const bf16* __restrict__ A, const bf16* __restrict__ Bt,
              const float* __restrict__ bias, float* __restrict__ C)
{
  __shared__ __attribute__((aligned(16))) bf16 As[8192];
  __shared__ __attribute__((aligned(16))) bf16 Bs[8192];
  const int tid = threadIdx.x;
  const int w = tid >> 6, l = tid & 63;
  const int ll = l & 15, lh = l >> 4;
  const int wm = w >> 1, wn = w & 1;

  const int idx = blockIdx.x;            // 0..1023
  const int xcd = idx & 7;
  const int local = idx >> 3;            // 0..127 = sub*32 + n*4 + msub
  const int msub = local & 3;
  const int nblk = (local >> 2) & 7;
  const int sub  = local >> 5;           // 0..3
  const int mblk = xcd * 16 + sub * 4 + msub;
  const int m0 = mblk * 128, n0 = nblk * 128;

  floatx4 acc[4][4];
#pragma unroll
  for (int i = 0; i < 4; ++i)
#pragma unroll
    for (int j = 0; j < 4; ++j) acc[i][j] = (floatx4)0.f;

  gemm_core_lds(A, Bt, m0, n0, As, Bs, acc, w, l);

#pragma unroll
  for (int mt = 0; mt < 4; ++mt) {
#pragma unroll
    for (int nt = 0; nt < 4; ++nt) {
      const int col = n0 + wn * 64 + nt * 16 + ll;
      const float bvv = bias[col];
#pragma unroll
      for (int r = 0; r < 4; ++r) {
        const int row = m0 + wm * 64 + mt * 16 + lh * 4 + r;
        C[(size_t)row * D_MODEL + col] = acc[mt][nt][r] + bvv;
      }
    }
  }
}

// ---------------- kernel A: QK^T + softmax -> normalized P (bf16) ----------------
// One block per (q-half, window, batch): 64 q rows x 128 keys, K=1024 contraction.
// Same global_load_lds single-buffer 2-barrier staging as the GEMM core.
__global__ __launch_bounds__(256)
void qk_softmax(const bf16* __restrict__ qb, const bf16* __restrict__ kb,
                bf16* __restrict__ Pg)
{
  __shared__ __attribute__((aligned(16))) bf16 As[4096];   // Q 64x64, 8KB
  __shared__ __attribute__((aligned(16))) bf16 Bs[8192];   // K 128x64, 16KB
  __shared__ float redM[4][64];
  __shared__ float redS[4][64];

  const int tid = threadIdx.x;
  const int w = tid >> 6, l = tid & 63, ll = l & 15, lh = l >> 4;
  const int wh = blockIdx.x;                 // 0..125
  const int win = wh >> 1, half = wh & 1;
  const int b = blockIdx.y;

  const bf16* Aq = qb + ((size_t)b * SEQ + win * 64 + half * 64) * D_MODEL
                 + (size_t)ll * D_MODEL + lh * 8;
  const bf16* Ak = kb + ((size_t)b * SEQ + win * 64) * D_MODEL
                 + (size_t)ll * D_MODEL + lh * 8;

  floatx4 acc[4][2];
#pragma unroll
  for (int i = 0; i < 4; ++i)
#pragma unroll
    for (int j = 0; j < 2; ++j) acc[i][j] = (floatx4)0.f;

  for (int t = 0; t < 16; ++t) {
    const int c0 = t << 6;
#pragma unroll
    for (int i = 0; i < 2; ++i) {            // Q: 8 frags (4 m x 2 kk)
      const int f = w * 2 + i;
      const int mt = f & 3, kk = f >> 2;
      async_ld16(Aq + (size_t)(mt * 16) * D_MODEL + (c0 + kk * 32),
                 &As[f * 512 + l * 8]);
    }
#pragma unroll
    for (int i = 0; i < 4; ++i) {            // K: 16 frags (8 n x 2 kk)
      const int f = w * 4 + i;
      const int mt = f & 7, kk = f >> 3;
      async_ld16(Ak + (size_t)(mt * 16) * D_MODEL + (c0 + kk * 32),
                 &Bs[f * 512 + l * 8]);
    }
    __syncthreads();
#pragma unroll
    for (int kk = 0; kk < 2; ++kk) {
      bf16x8 af[4], bfr[2];
#pragma unroll
      for (int tt = 0; tt < 4; ++tt)
        af[tt]  = *(const bf16x8*)&As[(kk * 4 + tt) * 512 + l * 8];
#pragma unroll
      for (int tt = 0; tt < 2; ++tt)
        bfr[tt] = *(const bf16x8*)&Bs[(kk * 8 + w * 2 + tt) * 512 + l * 8];
#pragma unroll
      for (int mt = 0; mt < 4; ++mt)
#pragma unroll
        for (int nt = 0; nt < 2; ++nt)
          acc[mt][nt] = __builtin_amdgcn_mfma_f32_16x16x32_bf16(af[mt], bfr[nt], acc[mt][nt], 0, 0, 0);
    }
    __syncthreads();
  }

  // scale by 1/sqrt(HEAD_DIM)=0.125
#pragma unroll
  for (int mt = 0; mt < 4; ++mt)
#pragma unroll
    for (int nt = 0; nt < 2; ++nt)
#pragma unroll
      for (int r = 0; r < 4; ++r) acc[mt][nt][r] *= 0.125f;

#pragma unroll
  for (int mt = 0; mt < 4; ++mt)
#pragma unroll
    for (int r = 0; r < 4; ++r) {
      float m = fmaxf(acc[mt][0][r], acc[mt][1][r]);
      m = fmaxf(m, __shfl_xor(m, 1));
      m = fmaxf(m, __shfl_xor(m, 2));
      m = fmaxf(m, __shfl_xor(m, 4));
      m = fmaxf(m, __shfl_xor(m, 8));
      if (ll == 0) redM[w][mt * 16 + lh * 4 + r] = m;
    }
  __syncthreads();

#pragma unroll
  for (int mt = 0; mt < 4; ++mt)
#pragma unroll
    for (int r = 0; r < 4; ++r) {
      const int row = mt * 16 + lh * 4 + r;
      const float m = fmaxf(fmaxf(redM[0][row], redM[1][row]),
                            fmaxf(redM[2][row], redM[3][row]));
      const float e0 = __expf(acc[mt][0][r] - m);
      const float e1 = __expf(acc[mt][1][r] - m);
      acc[mt][0][r] = e0; acc[mt][1][r] = e1;
      float s = e0 + e1;
      s += __shfl_xor(s, 1);
      s += __shfl_xor(s, 2);
      s += __shfl_xor(s, 4);
      s += __shfl_xor(s, 8);
      if (ll == 0) redS[w][row] = s;
    }
  __syncthreads();

  bf16* Pb = Pg + ((size_t)(b * NWIN + win) * 128 + half * 64) * 128;
#pragma unroll
  for (int mt = 0; mt < 4; ++mt)
#pragma unroll
    for (int r = 0; r < 4; ++r) {
      const int row = mt * 16 + lh * 4 + r;
      const float inv = 1.f / (redS[0][row] + redS[1][row] + redS[2][row] + redS[3][row]);
#pragma unroll
      for (int nt = 0; nt < 2; ++nt)
        Pb[(size_t)row * 128 + w * 32 + nt * 16 + ll] = (bf16)(acc[mt][nt][r] * inv);
    }
}

// ---------------- kernel B: gather-form P@V, averaged, direct bf16 store ----------
__global__ __launch_bounds__(256)
void pv_gather(const bf16* __restrict__ Pg, const bf16* __restrict__ vt,
               bf16* __restrict__ ab)
{
  __shared__ __attribute__((aligned(16))) bf16 As[4096];   // P 64x64, 8KB
  __shared__ __attribute__((aligned(16))) bf16 Bs[8192];   // Vt 128x64, 16KB

  const int tid = threadIdx.x;
  const int w = tid >> 6, l = tid & 63, ll = l & 15, lh = l >> 4;
  const int d0 = blockIdx.x * 128;           // 0..7
  const int h  = blockIdx.y;                 // 0..63
  const int b  = blockIdx.z;

  int wseg[2], roff[2];
  int nseg = 0;
  if (h >= 1)        { wseg[nseg] = h - 1; roff[nseg] = 64; ++nseg; }
  if (h <= NWIN - 1) { wseg[nseg] = h;     roff[nseg] = 0;  ++nseg; }
  const float scale = (nseg == 2) ? 0.5f : 1.0f;

  floatx4 acc[4][2];
#pragma unroll
  for (int i = 0; i < 4; ++i)
#pragma unroll
    for (int j = 0; j < 2; ++j) acc[i][j] = (floatx4)0.f;

  for (int sg = 0; sg < nseg; ++sg) {
    const bf16* Pseg = Pg + ((size_t)(b * NWIN + wseg[sg]) * 128 + roff[sg]) * 128;
    const bf16* Vseg = vt + ((size_t)b * D_MODEL + d0) * SEQ + wseg[sg] * 64;
    for (int c0 = 0; c0 < 128; c0 += 64) {
#pragma unroll
      for (int i = 0; i < 2; ++i) {          // P: 8 frags (4 m x 2 kk)
        const int f = w * 2 + i;
        const int mt = f & 3, kk = f >> 2;
        async_ld16(Pseg + (size_t)(mt * 16 + ll) * 128 + (c0 + kk * 32 + lh * 8),
                   &As[f * 512 + l * 8]);
      }
#pragma unroll
      for (int i = 0; i < 4; ++i) {          // Vt: 16 frags (8 n x 2 kk)
        const int f = w * 4 + i;
        const int mt = f & 7, kk = f >> 3;
        async_ld16(Vseg + (size_t)(mt * 16 + ll) * SEQ + (c0 + kk * 32 + lh * 8),
                   &Bs[f * 512 + l * 8]);
      }
      __syncthreads();
#pragma unroll
      for (int kk = 0; kk < 2; ++kk) {
        bf16x8 af[4], bfr[2];
#pragma unroll
        for (int t = 0; t < 4; ++t)
          af[t]  = *(const bf16x8*)&As[(kk * 4 + t) * 512 + l * 8];
#pragma unroll
        for (int t = 0; t < 2; ++t)
          bfr[t] = *(const bf16x8*)&Bs[(kk * 8 + w * 2 + t) * 512 + l * 8];
#pragma unroll
        for (int mt = 0; mt < 4; ++mt)
#pragma unroll
          for (int nt = 0; nt < 2; ++nt)
            acc[mt][nt] = __builtin_amdgcn_mfma_f32_16x16x32_bf16(af[mt], bfr[nt], acc[mt][nt], 0, 0, 0);
      }
      __syncthreads();
    }
  }

#pragma unroll
  for (int mt = 0; mt < 4; ++mt)
#pragma unroll
    for (int nt = 0; nt < 2; ++nt)
#pragma unroll
      for (int r = 0; r < 4; ++r) {
        const int row = h * 64 + mt * 16 + lh * 4 + r;
        const int col = d0 + w * 32 + nt * 16 + ll;
        ab[((size_t)b * SEQ + row) * D_MODEL + col] = (bf16)(acc[mt][nt][r] * scale);
      }
}

// ---------------- launcher ----------------
extern "C" void kernel_launch(void* const* d_in, const int* in_sizes, int n_in,
                              void* d_out, int out_size, void* d_ws, size_t ws_size,
                              hipStream_t stream)
{
  (void)in_sizes; (void)n_in; (void)out_size;

  const float* x  = (const float*)d_in[0];
  const float* Wq = (const float*)d_in[1];
  const float* bq = (const float*)d_in[2];
  const float* Wk = (const float*)d_in[3];
  const float* bk = (const float*)d_in[4];
  const float* Wv = (const float*)d_in[5];
  const float* bv = (const float*)d_in[6];
  const float* Wo = (const float*)d_in[7];
  const float* bo = (const float*)d_in[8];

  // workspace layout (bytes): xb 32M | wt 8M | qb 32M | kb 32M | vt 32M | ab 32M = 168 MiB
  // P (8.26 MB) aliases xb: xb's last use is gemm_qkv, P's first write is after.
  if (ws_size < (size_t)176160768) return;
  char* ws = (char*)d_ws;
  bf16* xb = (bf16*)(ws);
  bf16* pb = (bf16*)(ws);                  // P[b][win][128][128] bf16, aliases xb
  bf16* wt = (bf16*)(ws + 33554432);
  bf16* qb = (bf16*)(ws + 41943040);
  bf16* kb = (bf16*)(ws + 75497472);
  bf16* vt = (bf16*)(ws + 109051904);
  bf16* ab = (bf16*)(ws + 142606336);

  cvt_x_kernel<<<16384, 256, 0, stream>>>(x, xb);
  cvt_wt_kernel<<<dim3(32, 32, 4), 256, 0, stream>>>(Wq, Wk, Wv, Wo, wt);

  gemm_qkv<<<3072, 256, 0, stream>>>(xb, wt, bq, bk, bv, qb, kb, vt);

  qk_softmax<<<dim3(126, BATCH), 256, 0, stream>>>(qb, kb, pb);
  pv_gather<<<dim3(8, 64, BATCH), 256, 0, stream>>>(pb, vt, ab);

  gemm_out<<<1024, 256, 0, stream>>>(ab, wt + 3145728, bo, (float*)d_out);
}

// Round 2
// 441.460 us; speedup vs baseline: 1.1287x; 1.1202x over previous
//
#include <hip/hip_runtime.h>
#include <stdint.h>
#include <stddef.h>

#define D_MODEL 1024
#define SEQ     4096
#define BATCH   4
#define MTOT    (BATCH*SEQ)     // 16384
#define NWIN    63

typedef __bf16 bf16;
typedef __bf16 bf16x8 __attribute__((ext_vector_type(8)));
typedef __bf16 bf16x4 __attribute__((ext_vector_type(4)));
typedef float  floatx4 __attribute__((ext_vector_type(4)));

// async global->LDS, 16B per lane. LDS dest must be wave-uniform base + lane*16.
__device__ __forceinline__ void async_ld16(const void* g, void* l) {
  __builtin_amdgcn_global_load_lds(
      (const __attribute__((address_space(1))) unsigned int*)g,
      (__attribute__((address_space(3))) unsigned int*)l,
      16, 0, 0);
}

// ---------------- elementwise converts ----------------

__global__ __launch_bounds__(256)
void cvt_x_kernel(const float* __restrict__ x, bf16* __restrict__ xb)
{
  const int i = blockIdx.x * 256 + threadIdx.x;   // exactly 4M threads (16M elems /4)
  const float4 v = ((const float4*)x)[i];
  bf16x4 o = { (bf16)v.x, (bf16)v.y, (bf16)v.z, (bf16)v.w };
  ((bf16x4*)xb)[i] = o;
}

// W (fp32, [K][N]) -> Wt (bf16, [N][K]), packed: rows 0..1023=Wq^T, ..., 3072..4095=Wo^T
__global__ __launch_bounds__(256)
void cvt_wt_kernel(const float* __restrict__ W0, const float* __restrict__ W1,
                   const float* __restrict__ W2, const float* __restrict__ W3,
                   bf16* __restrict__ wt)
{
  __shared__ float tile[32][33];
  const float* Wsel = (blockIdx.z == 0) ? W0 : (blockIdx.z == 1) ? W1
                    : (blockIdx.z == 2) ? W2 : W3;
  bf16* Wt = wt + (size_t)blockIdx.z * D_MODEL * D_MODEL;
  const int tx = threadIdx.x & 31, ty = threadIdx.x >> 5;  // 32 x 8
  const int tn = blockIdx.x * 32, tk = blockIdx.y * 32;
#pragma unroll
  for (int j = 0; j < 32; j += 8)
    tile[ty + j][tx] = Wsel[(size_t)(tk + ty + j) * D_MODEL + (tn + tx)];
  __syncthreads();
#pragma unroll
  for (int j = 0; j < 32; j += 8)
    Wt[(size_t)(tn + ty + j) * D_MODEL + (tk + tx)] = (bf16)tile[tx][ty + j];
}

// ---------------- GEMM core: 256x256 tile, BK=32, counted-vmcnt pipeline --------
// 8 waves (2M x 4N), 512 threads. Per wave: 128x64 output = acc[8][4].
// LDS: A,B each 2 x 16KB double buffer (64KB total).
// Schedule per K-tile t:
//   s_waitcnt vmcnt(4)   <- tile t's 4 loads landed; tile t+1's 4 stay IN FLIGHT
//   s_barrier            <- cross-wave: all contributions to tile t landed
//   12 x ds_read_b128 ; setprio(1) ; 32 x MFMA ; setprio(0)
//   s_barrier            <- all reads of buf[t&1] done
//   issue tile t+2 -> buf[t&1]   (buffer just vacated; never races)
// vmcnt never drains to 0 in the main loop (T4); loads span ~1.5 iterations.
__device__ __forceinline__ void stage_tile(const bf16* __restrict__ Ab,
                                           const bf16* __restrict__ Bb,
                                           bf16* As, bf16* Bs, int t, int buf,
                                           int w, int l)
{
  const int k0 = t << 5;
  bf16* Ad = As + buf * 8192;
  bf16* Bd = Bs + buf * 8192;
#pragma unroll
  for (int i = 0; i < 2; ++i) {
    const int f = w * 2 + i;                 // frag 0..15: rows f*16..f*16+15, cols k0..k0+31
    async_ld16(Ab + (size_t)(f * 16) * D_MODEL + k0, Ad + f * 512 + l * 8);
    async_ld16(Bb + (size_t)(f * 16) * D_MODEL + k0, Bd + f * 512 + l * 8);
  }
}

__device__ __forceinline__ void gemm_core_256(const bf16* __restrict__ A,
                                              const bf16* __restrict__ Bt,
                                              int m0, int n0,
                                              bf16* As, bf16* Bs,
                                              floatx4 (&acc)[8][4],
                                              int w, int l)
{
  const int ll = l & 15, lh = l >> 4;
  const int wm = w >> 2, wn = w & 3;
  const bf16* Ab = A  + (size_t)(m0 + ll) * D_MODEL + lh * 8;
  const bf16* Bb = Bt + (size_t)(n0 + ll) * D_MODEL + lh * 8;

  stage_tile(Ab, Bb, As, Bs, 0, 0, w, l);
  stage_tile(Ab, Bb, As, Bs, 1, 1, w, l);

  for (int t = 0; t < 32; ++t) {             // K = 1024 = 32 * 32
    if (t < 31) asm volatile("s_waitcnt vmcnt(4)" ::: "memory");
    else        asm volatile("s_waitcnt vmcnt(0)" ::: "memory");
    __builtin_amdgcn_s_barrier();
    __builtin_amdgcn_sched_barrier(0);
    const bf16* Ac = As + (t & 1) * 8192;
    const bf16* Bc = Bs + (t & 1) * 8192;
    bf16x8 af[8], bfr[4];
#pragma unroll
    for (int mt = 0; mt < 8; ++mt)
      af[mt]  = *(const bf16x8*)&Ac[(wm * 8 + mt) * 512 + l * 8];
#pragma unroll
    for (int nt = 0; nt < 4; ++nt)
      bfr[nt] = *(const bf16x8*)&Bc[(wn * 4 + nt) * 512 + l * 8];
    __builtin_amdgcn_s_setprio(1);
#pragma unroll
    for (int mt = 0; mt < 8; ++mt)
#pragma unroll
      for (int nt = 0; nt < 4; ++nt)
        acc[mt][nt] = __builtin_amdgcn_mfma_f32_16x16x32_bf16(af[mt], bfr[nt], acc[mt][nt], 0, 0, 0);
    __builtin_amdgcn_s_setprio(0);
    __builtin_amdgcn_sched_barrier(0);
    __builtin_amdgcn_s_barrier();
    __builtin_amdgcn_sched_barrier(0);
    if (t + 2 < 32) stage_tile(Ab, Bb, As, Bs, t + 2, t & 1, w, l);
  }
}

// ---------------- fused QKV projection GEMM ----------------
__global__ __launch_bounds__(512, 2)
void gemm_qkv(const bf16* __restrict__ A, const bf16* __restrict__ Bt,
              const float* __restrict__ bq, const float* __restrict__ bk,
              const float* __restrict__ bv,
              bf16* __restrict__ qo, bf16* __restrict__ ko, bf16* __restrict__ vto)
{
  __shared__ __attribute__((aligned(16))) bf16 As[16384];  // 2 x 16KB
  __shared__ __attribute__((aligned(16))) bf16 Bs[16384];
  const int tid = threadIdx.x;
  const int w = tid >> 6, l = tid & 63;
  const int ll = l & 15, lh = l >> 4;
  const int wm = w >> 2, wn = w & 3;

  const int idx = blockIdx.x;            // 0..767 = 8 xcd x 96
  const int xcd = idx & 7;
  const int local = idx >> 3;            // 0..95
  const int msub = local & 7;
  const int nblk = local >> 3;           // 0..11
  const int mblk = xcd * 8 + msub;       // 0..63
  const int m0 = mblk * 256, n0 = nblk * 256;

  floatx4 acc[8][4];
#pragma unroll
  for (int i = 0; i < 8; ++i)
#pragma unroll
    for (int j = 0; j < 4; ++j) acc[i][j] = (floatx4)0.f;

  gemm_core_256(A, Bt, m0, n0, As, Bs, acc, w, l);

  const int sel = n0 >> 10;              // 0=q 1=k 2=v (block-uniform; 1024%256==0)
  const int ncl = n0 & 1023;
  const float* bias = (sel == 0) ? bq : (sel == 1) ? bk : bv;

#pragma unroll
  for (int mt = 0; mt < 8; ++mt) {
#pragma unroll
    for (int nt = 0; nt < 4; ++nt) {
      const int colL = ncl + wn * 64 + nt * 16 + ll;
      const float bvv = bias[colL];
#pragma unroll
      for (int r = 0; r < 4; ++r) {
        const int row = m0 + wm * 128 + mt * 16 + lh * 4 + r;
        const float v = acc[mt][nt][r] + bvv;
        if (sel == 0) {
          qo[(size_t)row * D_MODEL + colL] = (bf16)v;
        } else if (sel == 1) {
          ko[(size_t)row * D_MODEL + colL] = (bf16)v;
        } else {
          const int bb = row >> 12, s = row & 4095;
          vto[((size_t)bb * D_MODEL + colL) * SEQ + s] = (bf16)v;
        }
      }
    }
  }
}

// ---------------- output projection GEMM (fp32 out) ----------------
__global__ __launch_bounds__(512, 2)
void gemm_out(const bf16* __restrict__ A, const bf16* __restrict__ Bt,
              const float* __restrict__ bias, float* __restrict__ C)
{
  __shared__ __attribute__((aligned(16))) bf16 As[16384];
  __shared__ __attribute__((aligned(16))) bf16 Bs[16384];
  const int tid = threadIdx.x;
  const int w = tid >> 6, l = tid & 63;
  const int ll = l & 15, lh = l >> 4;
  const int wm = w >> 2, wn = w & 3;

  const int idx = blockIdx.x;            // 0..255 = 8 xcd x 32
  const int xcd = idx & 7;
  const int local = idx >> 3;            // 0..31
  const int msub = local & 7;
  const int nblk = local >> 3;           // 0..3
  const int mblk = xcd * 8 + msub;       // 0..63
  const int m0 = mblk * 256, n0 = nblk * 256;

  floatx4 acc[8][4];
#pragma unroll
  for (int i = 0; i < 8; ++i)
#pragma unroll
    for (int j = 0; j < 4; ++j) acc[i][j] = (floatx4)0.f;

  gemm_core_256(A, Bt, m0, n0, As, Bs, acc, w, l);

#pragma unroll
  for (int mt = 0; mt < 8; ++mt) {
#pragma unroll
    for (int nt = 0; nt < 4; ++nt) {
      const int col = n0 + wn * 64 + nt * 16 + ll;
      const float bvv = bias[col];
#pragma unroll
      for (int r = 0; r < 4; ++r) {
        const int row = m0 + wm * 128 + mt * 16 + lh * 4 + r;
        C[(size_t)row * D_MODEL + col] = acc[mt][nt][r] + bvv;
      }
    }
  }
}

// ---------------- kernel A: QK^T + softmax -> normalized P (bf16) ----------------
// One block per (q-half, window, batch): 64 q rows x 128 keys, K=1024 contraction.
// Counted-vmcnt double-buffered staging (BK=64, vmcnt(6)).
__global__ __launch_bounds__(256)
void qk_softmax(const bf16* __restrict__ qb, const bf16* __restrict__ kb,
                bf16* __restrict__ Pg)
{
  __shared__ __attribute__((aligned(16))) bf16 As[8192];   // Q 2 x (64x64), 16KB
  __shared__ __attribute__((aligned(16))) bf16 Bs[16384];  // K 2 x (128x64), 32KB
  __shared__ float redM[4][64];
  __shared__ float redS[4][64];

  const int tid = threadIdx.x;
  const int w = tid >> 6, l = tid & 63, ll = l & 15, lh = l >> 4;
  const int wh = blockIdx.x;                 // 0..125
  const int win = wh >> 1, half = wh & 1;
  const int b = blockIdx.y;

  const bf16* Aq = qb + ((size_t)b * SEQ + win * 64 + half * 64) * D_MODEL
                 + (size_t)ll * D_MODEL + lh * 8;
  const bf16* Ak = kb + ((size_t)b * SEQ + win * 64) * D_MODEL
                 + (size_t)ll * D_MODEL + lh * 8;

  floatx4 acc[4][2];
#pragma unroll
  for (int i = 0; i < 4; ++i)
#pragma unroll
    for (int j = 0; j < 2; ++j) acc[i][j] = (floatx4)0.f;

  // stage: Q 2 issues + K 4 issues per thread per K-tile (BK=64)
  auto stage = [&](int t, int buf) {
    const int c0 = t << 6;
    bf16* Ad = As + buf * 4096;
    bf16* Bd = Bs + buf * 8192;
#pragma unroll
    for (int i = 0; i < 2; ++i) {            // Q: 8 frags (4 m x 2 kk)
      const int f = w * 2 + i;
      const int mt = f & 3, kk = f >> 2;
      async_ld16(Aq + (size_t)(mt * 16) * D_MODEL + (c0 + kk * 32),
                 Ad + f * 512 + l * 8);
    }
#pragma unroll
    for (int i = 0; i < 4; ++i) {            // K: 16 frags (8 n x 2 kk)
      const int f = w * 4 + i;
      const int mt = f & 7, kk = f >> 3;
      async_ld16(Ak + (size_t)(mt * 16) * D_MODEL + (c0 + kk * 32),
                 Bd + f * 512 + l * 8);
    }
  };

  stage(0, 0);
  stage(1, 1);

  for (int t = 0; t < 16; ++t) {
    if (t < 15) asm volatile("s_waitcnt vmcnt(6)" ::: "memory");
    else        asm volatile("s_waitcnt vmcnt(0)" ::: "memory");
    __builtin_amdgcn_s_barrier();
    __builtin_amdgcn_sched_barrier(0);
    const bf16* Ac = As + (t & 1) * 4096;
    const bf16* Bc = Bs + (t & 1) * 8192;
#pragma unroll
    for (int kk = 0; kk < 2; ++kk) {
      bf16x8 af[4], bfr[2];
#pragma unroll
      for (int tt = 0; tt < 4; ++tt)
        af[tt]  = *(const bf16x8*)&Ac[(kk * 4 + tt) * 512 + l * 8];
#pragma unroll
      for (int tt = 0; tt < 2; ++tt)
        bfr[tt] = *(const bf16x8*)&Bc[(kk * 8 + w * 2 + tt) * 512 + l * 8];
      __builtin_amdgcn_s_setprio(1);
#pragma unroll
      for (int mt = 0; mt < 4; ++mt)
#pragma unroll
        for (int nt = 0; nt < 2; ++nt)
          acc[mt][nt] = __builtin_amdgcn_mfma_f32_16x16x32_bf16(af[mt], bfr[nt], acc[mt][nt], 0, 0, 0);
      __builtin_amdgcn_s_setprio(0);
    }
    __builtin_amdgcn_sched_barrier(0);
    __builtin_amdgcn_s_barrier();
    __builtin_amdgcn_sched_barrier(0);
    if (t + 2 < 16) stage(t + 2, t & 1);
  }

  // scale by 1/sqrt(HEAD_DIM)=0.125
#pragma unroll
  for (int mt = 0; mt < 4; ++mt)
#pragma unroll
    for (int nt = 0; nt < 2; ++nt)
#pragma unroll
      for (int r = 0; r < 4; ++r) acc[mt][nt][r] *= 0.125f;

#pragma unroll
  for (int mt = 0; mt < 4; ++mt)
#pragma unroll
    for (int r = 0; r < 4; ++r) {
      float m = fmaxf(acc[mt][0][r], acc[mt][1][r]);
      m = fmaxf(m, __shfl_xor(m, 1));
      m = fmaxf(m, __shfl_xor(m, 2));
      m = fmaxf(m, __shfl_xor(m, 4));
      m = fmaxf(m, __shfl_xor(m, 8));
      if (ll == 0) redM[w][mt * 16 + lh * 4 + r] = m;
    }
  __syncthreads();

#pragma unroll
  for (int mt = 0; mt < 4; ++mt)
#pragma unroll
    for (int r = 0; r < 4; ++r) {
      const int row = mt * 16 + lh * 4 + r;
      const float m = fmaxf(fmaxf(redM[0][row], redM[1][row]),
                            fmaxf(redM[2][row], redM[3][row]));
      const float e0 = __expf(acc[mt][0][r] - m);
      const float e1 = __expf(acc[mt][1][r] - m);
      acc[mt][0][r] = e0; acc[mt][1][r] = e1;
      float s = e0 + e1;
      s += __shfl_xor(s, 1);
      s += __shfl_xor(s, 2);
      s += __shfl_xor(s, 4);
      s += __shfl_xor(s, 8);
      if (ll == 0) redS[w][row] = s;
    }
  __syncthreads();

  bf16* Pb = Pg + ((size_t)(b * NWIN + win) * 128 + half * 64) * 128;
#pragma unroll
  for (int mt = 0; mt < 4; ++mt)
#pragma unroll
    for (int r = 0; r < 4; ++r) {
      const int row = mt * 16 + lh * 4 + r;
      const float inv = 1.f / (redS[0][row] + redS[1][row] + redS[2][row] + redS[3][row]);
#pragma unroll
      for (int nt = 0; nt < 2; ++nt)
        Pb[(size_t)row * 128 + w * 32 + nt * 16 + ll] = (bf16)(acc[mt][nt][r] * inv);
    }
}

// ---------------- kernel B: gather-form P@V, averaged, direct bf16 store ----------
__global__ __launch_bounds__(256)
void pv_gather(const bf16* __restrict__ Pg, const bf16* __restrict__ vt,
               bf16* __restrict__ ab)
{
  __shared__ __attribute__((aligned(16))) bf16 As[4096];   // P 64x64, 8KB
  __shared__ __attribute__((aligned(16))) bf16 Bs[8192];   // Vt 128x64, 16KB

  const int tid = threadIdx.x;
  const int w = tid >> 6, l = tid & 63, ll = l & 15, lh = l >> 4;
  const int d0 = blockIdx.x * 128;           // 0..7
  const int h  = blockIdx.y;                 // 0..63
  const int b  = blockIdx.z;

  int wseg[2], roff[2];
  int nseg = 0;
  if (h >= 1)        { wseg[nseg] = h - 1; roff[nseg] = 64; ++nseg; }
  if (h <= NWIN - 1) { wseg[nseg] = h;     roff[nseg] = 0;  ++nseg; }
  const float scale = (nseg == 2) ? 0.5f : 1.0f;

  floatx4 acc[4][2];
#pragma unroll
  for (int i = 0; i < 4; ++i)
#pragma unroll
    for (int j = 0; j < 2; ++j) acc[i][j] = (floatx4)0.f;

  for (int sg = 0; sg < nseg; ++sg) {
    const bf16* Pseg = Pg + ((size_t)(b * NWIN + wseg[sg]) * 128 + roff[sg]) * 128;
    const bf16* Vseg = vt + ((size_t)b * D_MODEL + d0) * SEQ + wseg[sg] * 64;
    for (int c0 = 0; c0 < 128; c0 += 64) {
#pragma unroll
      for (int i = 0; i < 2; ++i) {          // P: 8 frags (4 m x 2 kk)
        const int f = w * 2 + i;
        const int mt = f & 3, kk = f >> 2;
        async_ld16(Pseg + (size_t)(mt * 16 + ll) * 128 + (c0 + kk * 32 + lh * 8),
                   &As[f * 512 + l * 8]);
      }
#pragma unroll
      for (int i = 0; i < 4; ++i) {          // Vt: 16 frags (8 n x 2 kk)
        const int f = w * 4 + i;
        const int mt = f & 7, kk = f >> 3;
        async_ld16(Vseg + (size_t)(mt * 16 + ll) * SEQ + (c0 + kk * 32 + lh * 8),
                   &Bs[f * 512 + l * 8]);
      }
      __syncthreads();
#pragma unroll
      for (int kk = 0; kk < 2; ++kk) {
        bf16x8 af[4], bfr[2];
#pragma unroll
        for (int t = 0; t < 4; ++t)
          af[t]  = *(const bf16x8*)&As[(kk * 4 + t) * 512 + l * 8];
#pragma unroll
        for (int t = 0; t < 2; ++t)
          bfr[t] = *(const bf16x8*)&Bs[(kk * 8 + w * 2 + t) * 512 + l * 8];
#pragma unroll
        for (int mt = 0; mt < 4; ++mt)
#pragma unroll
          for (int nt = 0; nt < 2; ++nt)
            acc[mt][nt] = __builtin_amdgcn_mfma_f32_16x16x32_bf16(af[mt], bfr[nt], acc[mt][nt], 0, 0, 0);
      }
      __syncthreads();
    }
  }

#pragma unroll
  for (int mt = 0; mt < 4; ++mt)
#pragma unroll
    for (int nt = 0; nt < 2; ++nt)
#pragma unroll
      for (int r = 0; r < 4; ++r) {
        const int row = h * 64 + mt * 16 + lh * 4 + r;
        const int col = d0 + w * 32 + nt * 16 + ll;
        ab[((size_t)b * SEQ + row) * D_MODEL + col] = (bf16)(acc[mt][nt][r] * scale);
      }
}

// ---------------- launcher ----------------
extern "C" void kernel_launch(void* const* d_in, const int* in_sizes, int n_in,
                              void* d_out, int out_size, void* d_ws, size_t ws_size,
                              hipStream_t stream)
{
  (void)in_sizes; (void)n_in; (void)out_size;

  const float* x  = (const float*)d_in[0];
  const float* Wq = (const float*)d_in[1];
  const float* bq = (const float*)d_in[2];
  const float* Wk = (const float*)d_in[3];
  const float* bk = (const float*)d_in[4];
  const float* Wv = (const float*)d_in[5];
  const float* bv = (const float*)d_in[6];
  const float* Wo = (const float*)d_in[7];
  const float* bo = (const float*)d_in[8];

  // workspace layout (bytes): xb 32M | wt 8M | qb 32M | kb 32M | vt 32M | ab 32M = 168 MiB
  // P (8.26 MB) aliases xb: xb's last use is gemm_qkv, P's first write is after.
  if (ws_size < (size_t)176160768) return;
  char* ws = (char*)d_ws;
  bf16* xb = (bf16*)(ws);
  bf16* pb = (bf16*)(ws);                  // P[b][win][128][128] bf16, aliases xb
  bf16* wt = (bf16*)(ws + 33554432);
  bf16* qb = (bf16*)(ws + 41943040);
  bf16* kb = (bf16*)(ws + 75497472);
  bf16* vt = (bf16*)(ws + 109051904);
  bf16* ab = (bf16*)(ws + 142606336);

  cvt_x_kernel<<<16384, 256, 0, stream>>>(x, xb);
  cvt_wt_kernel<<<dim3(32, 32, 4), 256, 0, stream>>>(Wq, Wk, Wv, Wo, wt);

  gemm_qkv<<<768, 512, 0, stream>>>(xb, wt, bq, bk, bv, qb, kb, vt);

  qk_softmax<<<dim3(126, BATCH), 256, 0, stream>>>(qb, kb, pb);
  pv_gather<<<dim3(8, 64, BATCH), 256, 0, stream>>>(pb, vt, ab);

  gemm_out<<<256, 512, 0, stream>>>(ab, wt + 3145728, bo, (float*)d_out);
}